// Round 4
// baseline (385.749 us; speedup 1.0000x reference)
//
#include <hip/hip_runtime.h>

#define Hh 160
#define Ww 160
#define HW 25600
#define Bb 8
#define Cc 64
#define Oo 64
#define NPIX (Bb * HW)   // 204800

typedef __bf16 bf16x8 __attribute__((ext_vector_type(8)));
typedef float  f32x4  __attribute__((ext_vector_type(4)));
typedef float  f32x2  __attribute__((ext_vector_type(2)));

__device__ inline unsigned rnd_bf(float a) {
    unsigned u = __float_as_uint(a);
    return (u + 0x7FFFu + ((u >> 16) & 1u)) >> 16;   // RNE f32->bf16
}
__device__ inline unsigned pack_bf2(float a, float b) {
    return rnd_bf(a) | (rnd_bf(b) << 16);
}
__device__ inline f32x2 up2(unsigned u) {
    f32x2 r;
    r.x = __uint_as_float(u << 16);
    r.y = __uint_as_float(u & 0xffff0000u);
    return r;
}
__device__ inline unsigned blend4(unsigned u00, unsigned u01, unsigned u10, unsigned u11,
                                  float w00, float w01, float w10, float w11) {
    f32x2 r = up2(u00) * w00 + up2(u01) * w01 + up2(u10) * w10 + up2(u11) * w11;
    return pack_bf2(r.x, r.y);
}
union UV { uint4 u; bf16x8 v; };
__device__ inline bf16x8 as_bf(uint4 u) { UV c; c.u = u; return c.v; }

// ---- prep: wtb[k][o 64][c] bf16 ; woffb[k][o pad32][c] bf16 ; BN fold ---------
__global__ __launch_bounds__(256) void prep_kernel(
    const float* __restrict__ w_dcn, const float* __restrict__ b_dcn,
    const float* __restrict__ w_off,
    const float* __restrict__ gamma, const float* __restrict__ beta,
    const float* __restrict__ run_mean, const float* __restrict__ run_var,
    unsigned short* __restrict__ wtb, unsigned short* __restrict__ woffb,
    float* __restrict__ scaleb)
{
    int i = blockIdx.x * 256 + threadIdx.x;
    if (i < 9 * Oo * Cc) {                 // wtb: [k][o][c]
        int k = i >> 12, rem = i & 4095;
        int o = rem >> 6, c = rem & 63;
        wtb[i] = (unsigned short)rnd_bf(w_dcn[(o * Cc + c) * 9 + k]);
    }
    if (i < 9 * 32 * Cc) {                 // woffb: [k][o pad32][c]
        int k = i >> 11, rem = i & 2047;
        int o = rem >> 6, c = rem & 63;
        float v = (o < 18) ? w_off[(o * Cc + c) * 9 + k] : 0.0f;
        woffb[i] = (unsigned short)rnd_bf(v);
    }
    if (i < Oo) {
        float inv = gamma[i] * rsqrtf(run_var[i] + 1e-5f);
        scaleb[i]      = inv;
        scaleb[Oo + i] = b_dcn[i] * inv + (beta[i] - run_mean[i] * inv);
    }
}

// ---- transpose x: NCHW fp32 -> NHWC bf16, LDS tile, coalesced both sides ------
__global__ __launch_bounds__(256, 8) void xpose_kernel(
    const float* __restrict__ x, unsigned short* __restrict__ xhwc)
{
    __shared__ float tile[64 * 65];
    int blk = blockIdx.x;                  // 3200
    int b = blk / 400, hw0 = (blk % 400) * 64;
    int t = threadIdx.x;
    int lane = t & 63, grp = t >> 6;

    const float* xp = x + (size_t)b * Cc * HW + hw0 + lane;
#pragma unroll
    for (int i = 0; i < 16; ++i) {
        int c = i * 4 + grp;
        tile[lane * 65 + c] = xp[(size_t)c * HW];
    }
    __syncthreads();

    int px  = t >> 2;                      // 0..63
    int ch0 = (t & 3) * 16;
    const float* row = tile + px * 65 + ch0;
    unsigned u[8];
#pragma unroll
    for (int j = 0; j < 8; ++j) u[j] = pack_bf2(row[2 * j], row[2 * j + 1]);
    unsigned short* dst = xhwc + ((size_t)(b * HW + hw0 + px)) * 64 + ch0;
    *(uint4*)dst       = make_uint4(u[0], u[1], u[2], u[3]);
    *(uint4*)(dst + 8) = make_uint4(u[4], u[5], u[6], u[7]);
}

// ---- fused: offset-conv(MFMA) + deform-sample + projection(MFMA) + BN + ReLU --
// 256 thr = 4 waves, 64 px/block. All fragments built in registers; LDS only
// for the offset handoff (stride 19 -> conflict-free). One barrier total.
__global__ __launch_bounds__(256, 3) void dcn_kernel(
    const unsigned short* __restrict__ xhwc,
    const unsigned short* __restrict__ wtb,
    const unsigned short* __restrict__ woffb,
    const float* __restrict__ b_off,
    const float* __restrict__ scaleb,
    float* __restrict__ out)
{
    __shared__ float offb[64 * 19];        // [px][18 offset channels]

    const int t = threadIdx.x;
    const int lane = t & 63, wv = t >> 6;
    const int m = lane & 15, quad = lane >> 4;

    int blk = blockIdx.x;
    int nb  = (blk & 7) * 400 + (blk >> 3);   // XCD slab swizzle: 1 image/XCD
    int b   = nb / 400;
    int hw0 = (nb % 400) * 64;
    int p   = wv * 16 + m;                 // this lane's pixel (shared by 4 quads)
    int hw  = hw0 + p;
    int h   = hw / Ww, w = hw % Ww;

    const size_t bbase = (size_t)b * HW;
    const unsigned short* xq = xhwc + bbase * 64 + quad * 8;   // lane's c-chunk base

    // ================= phase 1: offset conv (barrier-free) =================
    f32x4 oa0 = {0, 0, 0, 0}, oa1 = {0, 0, 0, 0};
#pragma unroll 1
    for (int k = 0; k < 9; ++k) {
        int hp = h + (k / 3) - 1, wp = w + (k % 3) - 1;
        bool ok = (hp >= 0) & (hp < Hh) & (wp >= 0) & (wp < Ww);
        int hps = min(max(hp, 0), Hh - 1), wps = min(max(wp, 0), Ww - 1);
        const unsigned short* src = xq + (size_t)(hps * Ww + wps) * 64;
        uint4 r0 = *(const uint4*)(src);
        uint4 r1 = *(const uint4*)(src + 32);
        if (!ok) { r0 = make_uint4(0,0,0,0); r1 = make_uint4(0,0,0,0); }
        bf16x8 a0 = as_bf(r0), a1 = as_bf(r1);

        const unsigned short* wb = woffb + k * 2048 + quad * 8;
        bf16x8 b00 = *(const bf16x8*)(wb + m * 64);
        bf16x8 b01 = *(const bf16x8*)(wb + m * 64 + 32);
        bf16x8 b10 = *(const bf16x8*)(wb + (m + 16) * 64);
        bf16x8 b11 = *(const bf16x8*)(wb + (m + 16) * 64 + 32);
        oa0 = __builtin_amdgcn_mfma_f32_16x16x32_bf16(a0, b00, oa0, 0, 0, 0);
        oa0 = __builtin_amdgcn_mfma_f32_16x16x32_bf16(a1, b01, oa0, 0, 0, 0);
        oa1 = __builtin_amdgcn_mfma_f32_16x16x32_bf16(a0, b10, oa1, 0, 0, 0);
        oa1 = __builtin_amdgcn_mfma_f32_16x16x32_bf16(a1, b11, oa1, 0, 0, 0);
    }
    // D layout: col(=o)=m, row(=pixel)=quad*4+r. Write offsets+bias to LDS.
    {
        float bo0 = b_off[m];
        float bo1 = (m < 2) ? b_off[16 + m] : 0.0f;
#pragma unroll
        for (int r = 0; r < 4; ++r) {
            int pp = wv * 16 + quad * 4 + r;
            offb[pp * 19 + m] = oa0[r] + bo0;
            if (m < 2) offb[pp * 19 + 16 + m] = oa1[r] + bo1;
        }
    }
    __syncthreads();     // the only barrier

    // ================= phase 2: deform sample + projection =================
    f32x4 c0 = {0,0,0,0}, c1 = {0,0,0,0}, c2 = {0,0,0,0}, c3 = {0,0,0,0};
#pragma unroll 1
    for (int k = 0; k < 9; ++k) {
        float offy = offb[p * 19 + 2 * k];
        float offx = offb[p * 19 + 2 * k + 1];
        float py = (float)(h + k / 3 - 1) + offy;
        float px = (float)(w + k % 3 - 1) + offx;
        float y0f = floorf(py), x0f = floorf(px);
        float fy = py - y0f, fx = px - x0f;
        int y0 = (int)y0f, x0i = (int)x0f;
        int y1 = y0 + 1, x1 = x0i + 1;
        bool vy0 = (y0 >= 0) & (y0 < Hh), vy1 = (y1 >= 0) & (y1 < Hh);
        bool vx0 = (x0i >= 0) & (x0i < Ww), vx1 = (x1 >= 0) & (x1 < Ww);
        float w00 = (vy0 & vx0) ? (1.0f - fy) * (1.0f - fx) : 0.0f;
        float w01 = (vy0 & vx1) ? (1.0f - fy) * fx : 0.0f;
        float w10 = (vy1 & vx0) ? fy * (1.0f - fx) : 0.0f;
        float w11 = (vy1 & vx1) ? fy * fx : 0.0f;
        int cy0 = min(max(y0, 0), Hh - 1), cy1 = min(max(y1, 0), Hh - 1);
        int cx0 = min(max(x0i, 0), Ww - 1), cx1 = min(max(x1, 0), Ww - 1);

        const unsigned short* s00 = xq + (size_t)(cy0 * Ww + cx0) * 64;
        const unsigned short* s01 = xq + (size_t)(cy0 * Ww + cx1) * 64;
        const unsigned short* s10 = xq + (size_t)(cy1 * Ww + cx0) * 64;
        const unsigned short* s11 = xq + (size_t)(cy1 * Ww + cx1) * 64;
        uint4 a00 = *(const uint4*)(s00), b00 = *(const uint4*)(s00 + 32);
        uint4 a01 = *(const uint4*)(s01), b01 = *(const uint4*)(s01 + 32);
        uint4 a10 = *(const uint4*)(s10), b10 = *(const uint4*)(s10 + 32);
        uint4 a11 = *(const uint4*)(s11), b11 = *(const uint4*)(s11 + 32);

        uint4 o0, o1;
        o0.x = blend4(a00.x, a01.x, a10.x, a11.x, w00, w01, w10, w11);
        o0.y = blend4(a00.y, a01.y, a10.y, a11.y, w00, w01, w10, w11);
        o0.z = blend4(a00.z, a01.z, a10.z, a11.z, w00, w01, w10, w11);
        o0.w = blend4(a00.w, a01.w, a10.w, a11.w, w00, w01, w10, w11);
        o1.x = blend4(b00.x, b01.x, b10.x, b11.x, w00, w01, w10, w11);
        o1.y = blend4(b00.y, b01.y, b10.y, b11.y, w00, w01, w10, w11);
        o1.z = blend4(b00.z, b01.z, b10.z, b11.z, w00, w01, w10, w11);
        o1.w = blend4(b00.w, b01.w, b10.w, b11.w, w00, w01, w10, w11);
        bf16x8 A0 = as_bf(o0), A1 = as_bf(o1);

        const unsigned short* wq = wtb + k * 4096 + quad * 8;
        bf16x8 B0, B1;
        B0 = *(const bf16x8*)(wq + m * 64);
        B1 = *(const bf16x8*)(wq + m * 64 + 32);
        c0 = __builtin_amdgcn_mfma_f32_16x16x32_bf16(A0, B0, c0, 0, 0, 0);
        c0 = __builtin_amdgcn_mfma_f32_16x16x32_bf16(A1, B1, c0, 0, 0, 0);
        B0 = *(const bf16x8*)(wq + (m + 16) * 64);
        B1 = *(const bf16x8*)(wq + (m + 16) * 64 + 32);
        c1 = __builtin_amdgcn_mfma_f32_16x16x32_bf16(A0, B0, c1, 0, 0, 0);
        c1 = __builtin_amdgcn_mfma_f32_16x16x32_bf16(A1, B1, c1, 0, 0, 0);
        B0 = *(const bf16x8*)(wq + (m + 32) * 64);
        B1 = *(const bf16x8*)(wq + (m + 32) * 64 + 32);
        c2 = __builtin_amdgcn_mfma_f32_16x16x32_bf16(A0, B0, c2, 0, 0, 0);
        c2 = __builtin_amdgcn_mfma_f32_16x16x32_bf16(A1, B1, c2, 0, 0, 0);
        B0 = *(const bf16x8*)(wq + (m + 48) * 64);
        B1 = *(const bf16x8*)(wq + (m + 48) * 64 + 32);
        c3 = __builtin_amdgcn_mfma_f32_16x16x32_bf16(A0, B0, c3, 0, 0, 0);
        c3 = __builtin_amdgcn_mfma_f32_16x16x32_bf16(A1, B1, c3, 0, 0, 0);
    }

    // ---- epilogue: direct float4 stores (D rows = 4 consecutive pixels) ----
#pragma unroll
    for (int nt = 0; nt < 4; ++nt) {
        f32x4 a = (nt == 0) ? c0 : (nt == 1) ? c1 : (nt == 2) ? c2 : c3;
        int o = nt * 16 + m;
        float sc = scaleb[o];
        float bs = scaleb[Oo + o];
        float4 r;
        r.x = fmaxf(a[0] * sc + bs, 0.0f);
        r.y = fmaxf(a[1] * sc + bs, 0.0f);
        r.z = fmaxf(a[2] * sc + bs, 0.0f);
        r.w = fmaxf(a[3] * sc + bs, 0.0f);
        float* op = out + ((size_t)b * Oo + o) * HW + hw0 + wv * 16 + quad * 4;
        *(float4*)op = r;
    }
}

extern "C" void kernel_launch(void* const* d_in, const int* in_sizes, int n_in,
                              void* d_out, int out_size, void* d_ws, size_t ws_size,
                              hipStream_t stream) {
    const float* x        = (const float*)d_in[0];
    const float* w_off    = (const float*)d_in[1];
    const float* b_off    = (const float*)d_in[2];
    const float* w_dcn    = (const float*)d_in[3];
    const float* b_dcn    = (const float*)d_in[4];
    const float* gamma    = (const float*)d_in[5];
    const float* beta     = (const float*)d_in[6];
    const float* run_mean = (const float*)d_in[7];
    const float* run_var  = (const float*)d_in[8];
    float* out = (float*)d_out;

    // workspace: xhwc (26.2 MB) | wtb | woffb | scaleb
    unsigned short* xhwc  = (unsigned short*)d_ws;
    unsigned short* wtb   = xhwc + (size_t)NPIX * 64;          // 9*64*64 bf16
    unsigned short* woffb = wtb + 9 * Oo * Cc;                 // 9*32*64 bf16
    float* scaleb         = (float*)(woffb + 9 * 32 * Cc);     // 128 floats

    prep_kernel<<<(9 * Oo * Cc + 255) / 256, 256, 0, stream>>>(
        w_dcn, b_dcn, w_off, gamma, beta, run_mean, run_var, wtb, woffb, scaleb);

    xpose_kernel<<<NPIX / 64, 256, 0, stream>>>(x, xhwc);

    dcn_kernel<<<NPIX / 64, 256, 0, stream>>>(xhwc, wtb, woffb, b_off, scaleb, out);
}

// Round 5
// 257.541 us; speedup vs baseline: 1.4978x; 1.4978x over previous
//
#include <hip/hip_runtime.h>

#define Hh 160
#define Ww 160
#define HW 25600
#define Bb 8
#define Cc 64
#define Oo 64
#define NPIX (Bb * HW)   // 204800
#define WROW 72          // shorts per padded LDS weight row (144 B)

typedef __bf16 bf16x8 __attribute__((ext_vector_type(8)));
typedef float  f32x4  __attribute__((ext_vector_type(4)));
typedef float  f32x2  __attribute__((ext_vector_type(2)));

__device__ inline unsigned rnd_bf(float a) {
    unsigned u = __float_as_uint(a);
    return (u + 0x7FFFu + ((u >> 16) & 1u)) >> 16;   // RNE f32->bf16 (prep only)
}
// fast round-half-up pack of two f32 -> packed bf16x2 (3 VALU ops)
__device__ inline unsigned pack_bf2(float a, float b) {
    unsigned ua = __float_as_uint(a) + 0x8000u;
    unsigned ub = __float_as_uint(b) + 0x8000u;
    return __builtin_amdgcn_perm(ub, ua, 0x07060302);
}
__device__ inline f32x2 up2(unsigned u) {
    f32x2 r;
    r.x = __uint_as_float(u << 16);
    r.y = __uint_as_float(u & 0xffff0000u);
    return r;
}
__device__ inline unsigned blend4(unsigned u00, unsigned u01, unsigned u10, unsigned u11,
                                  float w00, float w01, float w10, float w11) {
    f32x2 r = up2(u00) * w00 + up2(u01) * w01 + up2(u10) * w10 + up2(u11) * w11;
    return pack_bf2(r.x, r.y);
}
union UV { uint4 u; bf16x8 v; };
__device__ inline bf16x8 as_bf(uint4 u) { UV c; c.u = u; return c.v; }

// ---- prep: wtb[k][o 64][c] bf16 ; woffb[k][o pad32][c] bf16 ; BN fold ---------
__global__ __launch_bounds__(256) void prep_kernel(
    const float* __restrict__ w_dcn, const float* __restrict__ b_dcn,
    const float* __restrict__ w_off,
    const float* __restrict__ gamma, const float* __restrict__ beta,
    const float* __restrict__ run_mean, const float* __restrict__ run_var,
    unsigned short* __restrict__ wtb, unsigned short* __restrict__ woffb,
    float* __restrict__ scaleb)
{
    int i = blockIdx.x * 256 + threadIdx.x;
    if (i < 9 * Oo * Cc) {                 // wtb: [k][o][c]
        int k = i >> 12, rem = i & 4095;
        int o = rem >> 6, c = rem & 63;
        wtb[i] = (unsigned short)rnd_bf(w_dcn[(o * Cc + c) * 9 + k]);
    }
    if (i < 9 * 32 * Cc) {                 // woffb: [k][o pad32][c]
        int k = i >> 11, rem = i & 2047;
        int o = rem >> 6, c = rem & 63;
        float v = (o < 18) ? w_off[(o * Cc + c) * 9 + k] : 0.0f;
        woffb[i] = (unsigned short)rnd_bf(v);
    }
    if (i < Oo) {
        float inv = gamma[i] * rsqrtf(run_var[i] + 1e-5f);
        scaleb[i]      = inv;
        scaleb[Oo + i] = b_dcn[i] * inv + (beta[i] - run_mean[i] * inv);
    }
}

// ---- transpose x: NCHW fp32 -> NHWC bf16, LDS tile, coalesced both sides ------
__global__ __launch_bounds__(256, 4) void xpose_kernel(
    const float* __restrict__ x, unsigned short* __restrict__ xhwc)
{
    __shared__ float tile[64 * 65];
    int blk = blockIdx.x;                  // 3200
    int b = blk / 400, hw0 = (blk % 400) * 64;
    int t = threadIdx.x;
    int lane = t & 63, grp = t >> 6;

    const float* xp = x + (size_t)b * Cc * HW + hw0 + lane;
#pragma unroll
    for (int i = 0; i < 16; ++i) {
        int c = i * 4 + grp;
        tile[lane * 65 + c] = xp[(size_t)c * HW];
    }
    __syncthreads();

    int px  = t >> 2;                      // 0..63
    int ch0 = (t & 3) * 16;
    const float* row = tile + px * 65 + ch0;
    unsigned u[8];
#pragma unroll
    for (int j = 0; j < 8; ++j) u[j] = pack_bf2(row[2 * j], row[2 * j + 1]);
    unsigned short* dst = xhwc + ((size_t)(b * HW + hw0 + px)) * 64 + ch0;
    *(uint4*)dst       = make_uint4(u[0], u[1], u[2], u[3]);
    *(uint4*)(dst + 8) = make_uint4(u[4], u[5], u[6], u[7]);
}

// ---- fused: offset-conv(MFMA) + deform-sample + projection(MFMA) + BN + ReLU --
// 256 thr = 4 waves, 64 px/block. A-fragments built in registers (16-line
// gathers); B-weights double-buffered in LDS (padded rows), 1 barrier/tap.
__global__ __launch_bounds__(256, 4) void dcn_kernel(
    const unsigned short* __restrict__ xhwc,
    const unsigned short* __restrict__ wtb,     // [9][64][64]
    const unsigned short* __restrict__ woffb,   // [9][32][64]
    const float* __restrict__ b_off,
    const float* __restrict__ scaleb,
    float* __restrict__ out)
{
    __shared__ __align__(16) short wdcn[2 * 64 * WROW];   // 18432 B
    __shared__ __align__(16) short woff[2 * 32 * WROW];   //  9216 B
    __shared__ float offb[64 * 19];                       //  4864 B

    const int t = threadIdx.x;
    const int lane = t & 63, wv = t >> 6;
    const int m = lane & 15, quad = lane >> 4;

    int blk = blockIdx.x;
    int nb  = (blk & 7) * 400 + (blk >> 3);   // XCD slab swizzle: 1 image/XCD
    int b   = nb / 400;
    int hw0 = (nb % 400) * 64;
    int p   = wv * 16 + m;                 // this lane's pixel
    int hw  = hw0 + p;
    int h   = hw / Ww, w = hw % Ww;

    const size_t bbase = (size_t)b * HW;
    const unsigned short* xq = xhwc + bbase * 64 + quad * 8;
    const uint4* wtb4  = (const uint4*)wtb;
    const uint4* wofb4 = (const uint4*)woffb;

    // ================= phase 1: offset conv (dbuf LDS weights) =================
    f32x4 oa0 = {0,0,0,0}, oa1 = {0,0,0,0};
    {   // stage tap 0 -> buf 0 (32 rows x 64c = 256 chunks, 1/thread)
        uint4 v = wofb4[t];
        *(uint4*)((char*)woff + (t >> 3) * (WROW * 2) + (t & 7) * 16) = v;
    }
    __syncthreads();
#pragma unroll 1
    for (int k = 0; k < 9; ++k) {
        int cur = k & 1;
        if (k < 8) {   // stage tap k+1 into the other buffer
            uint4 v = wofb4[(k + 1) * 256 + t];
            *(uint4*)((char*)(woff + (cur ^ 1) * 32 * WROW)
                      + (t >> 3) * (WROW * 2) + (t & 7) * 16) = v;
        }
        int hp = h + (k / 3) - 1, wp = w + (k % 3) - 1;
        bool ok = (hp >= 0) & (hp < Hh) & (wp >= 0) & (wp < Ww);
        int hps = min(max(hp, 0), Hh - 1), wps = min(max(wp, 0), Ww - 1);
        const unsigned short* src = xq + (size_t)(hps * Ww + wps) * 64;
        uint4 r0 = *(const uint4*)(src);
        uint4 r1 = *(const uint4*)(src + 32);
        if (!ok) { r0 = make_uint4(0,0,0,0); r1 = make_uint4(0,0,0,0); }
        bf16x8 a0 = as_bf(r0), a1 = as_bf(r1);

        const short* wb = woff + cur * 32 * WROW + quad * 8;
        bf16x8 b00 = *(const bf16x8*)(wb + m * WROW);
        bf16x8 b01 = *(const bf16x8*)(wb + m * WROW + 32);
        bf16x8 b10 = *(const bf16x8*)(wb + (m + 16) * WROW);
        bf16x8 b11 = *(const bf16x8*)(wb + (m + 16) * WROW + 32);
        oa0 = __builtin_amdgcn_mfma_f32_16x16x32_bf16(a0, b00, oa0, 0, 0, 0);
        oa0 = __builtin_amdgcn_mfma_f32_16x16x32_bf16(a1, b01, oa0, 0, 0, 0);
        oa1 = __builtin_amdgcn_mfma_f32_16x16x32_bf16(a0, b10, oa1, 0, 0, 0);
        oa1 = __builtin_amdgcn_mfma_f32_16x16x32_bf16(a1, b11, oa1, 0, 0, 0);
        __syncthreads();   // reads of cur done before next iter overwrites it
    }

    // offsets -> LDS (stride 19 -> conflict-light); stage dcn tap 0 -> buf 0
    {
        float bo0 = b_off[m];
        float bo1 = (m < 2) ? b_off[16 + m] : 0.0f;
#pragma unroll
        for (int r = 0; r < 4; ++r) {
            int pp = wv * 16 + quad * 4 + r;
            offb[pp * 19 + m] = oa0[r] + bo0;
            if (m < 2) offb[pp * 19 + 16 + m] = oa1[r] + bo1;
        }
    }
    {   // 64 rows x 64c = 512 chunks, 2/thread
        uint4 v0 = wtb4[t], v1 = wtb4[t + 256];
        *(uint4*)((char*)wdcn + (t >> 3) * (WROW * 2) + (t & 7) * 16) = v0;
        int q = t + 256;
        *(uint4*)((char*)wdcn + (q >> 3) * (WROW * 2) + (q & 7) * 16) = v1;
    }
    __syncthreads();

    // ================= phase 2: deform sample + projection =================
    f32x4 c0 = {0,0,0,0}, c1 = {0,0,0,0}, c2 = {0,0,0,0}, c3 = {0,0,0,0};
#pragma unroll 1
    for (int k = 0; k < 9; ++k) {
        int cur = k & 1;
        if (k < 8) {   // stage tap k+1 into the other buffer
            const uint4* g = wtb4 + (k + 1) * 512;
            uint4 v0 = g[t], v1 = g[t + 256];
            char* base = (char*)(wdcn + (cur ^ 1) * 64 * WROW);
            *(uint4*)(base + (t >> 3) * (WROW * 2) + (t & 7) * 16) = v0;
            int q = t + 256;
            *(uint4*)(base + (q >> 3) * (WROW * 2) + (q & 7) * 16) = v1;
        }
        float offy = offb[p * 19 + 2 * k];
        float offx = offb[p * 19 + 2 * k + 1];
        float py = (float)(h + k / 3 - 1) + offy;
        float px = (float)(w + k % 3 - 1) + offx;
        float y0f = floorf(py), x0f = floorf(px);
        float fy = py - y0f, fx = px - x0f;
        int y0 = (int)y0f, x0i = (int)x0f;
        int y1 = y0 + 1, x1 = x0i + 1;
        bool vy0 = (y0 >= 0) & (y0 < Hh), vy1 = (y1 >= 0) & (y1 < Hh);
        bool vx0 = (x0i >= 0) & (x0i < Ww), vx1 = (x1 >= 0) & (x1 < Ww);
        float w00 = (vy0 & vx0) ? (1.0f - fy) * (1.0f - fx) : 0.0f;
        float w01 = (vy0 & vx1) ? (1.0f - fy) * fx : 0.0f;
        float w10 = (vy1 & vx0) ? fy * (1.0f - fx) : 0.0f;
        float w11 = (vy1 & vx1) ? fy * fx : 0.0f;
        int cy0 = min(max(y0, 0), Hh - 1), cy1 = min(max(y1, 0), Hh - 1);
        int cx0 = min(max(x0i, 0), Ww - 1), cx1 = min(max(x1, 0), Ww - 1);

        const unsigned short* s00 = xq + (size_t)(cy0 * Ww + cx0) * 64;
        const unsigned short* s01 = xq + (size_t)(cy0 * Ww + cx1) * 64;
        const unsigned short* s10 = xq + (size_t)(cy1 * Ww + cx0) * 64;
        const unsigned short* s11 = xq + (size_t)(cy1 * Ww + cx1) * 64;
        uint4 a00 = *(const uint4*)(s00), b00 = *(const uint4*)(s00 + 32);
        uint4 a01 = *(const uint4*)(s01), b01 = *(const uint4*)(s01 + 32);
        uint4 a10 = *(const uint4*)(s10), b10 = *(const uint4*)(s10 + 32);
        uint4 a11 = *(const uint4*)(s11), b11 = *(const uint4*)(s11 + 32);

        uint4 o0, o1;
        o0.x = blend4(a00.x, a01.x, a10.x, a11.x, w00, w01, w10, w11);
        o0.y = blend4(a00.y, a01.y, a10.y, a11.y, w00, w01, w10, w11);
        o0.z = blend4(a00.z, a01.z, a10.z, a11.z, w00, w01, w10, w11);
        o0.w = blend4(a00.w, a01.w, a10.w, a11.w, w00, w01, w10, w11);
        o1.x = blend4(b00.x, b01.x, b10.x, b11.x, w00, w01, w10, w11);
        o1.y = blend4(b00.y, b01.y, b10.y, b11.y, w00, w01, w10, w11);
        o1.z = blend4(b00.z, b01.z, b10.z, b11.z, w00, w01, w10, w11);
        o1.w = blend4(b00.w, b01.w, b10.w, b11.w, w00, w01, w10, w11);
        bf16x8 A0 = as_bf(o0), A1 = as_bf(o1);

        const short* wq = wdcn + cur * 64 * WROW + quad * 8;
        bf16x8 B0, B1;
        B0 = *(const bf16x8*)(wq + m * WROW);
        B1 = *(const bf16x8*)(wq + m * WROW + 32);
        c0 = __builtin_amdgcn_mfma_f32_16x16x32_bf16(A0, B0, c0, 0, 0, 0);
        c0 = __builtin_amdgcn_mfma_f32_16x16x32_bf16(A1, B1, c0, 0, 0, 0);
        B0 = *(const bf16x8*)(wq + (m + 16) * WROW);
        B1 = *(const bf16x8*)(wq + (m + 16) * WROW + 32);
        c1 = __builtin_amdgcn_mfma_f32_16x16x32_bf16(A0, B0, c1, 0, 0, 0);
        c1 = __builtin_amdgcn_mfma_f32_16x16x32_bf16(A1, B1, c1, 0, 0, 0);
        B0 = *(const bf16x8*)(wq + (m + 32) * WROW);
        B1 = *(const bf16x8*)(wq + (m + 32) * WROW + 32);
        c2 = __builtin_amdgcn_mfma_f32_16x16x32_bf16(A0, B0, c2, 0, 0, 0);
        c2 = __builtin_amdgcn_mfma_f32_16x16x32_bf16(A1, B1, c2, 0, 0, 0);
        B0 = *(const bf16x8*)(wq + (m + 48) * WROW);
        B1 = *(const bf16x8*)(wq + (m + 48) * WROW + 32);
        c3 = __builtin_amdgcn_mfma_f32_16x16x32_bf16(A0, B0, c3, 0, 0, 0);
        c3 = __builtin_amdgcn_mfma_f32_16x16x32_bf16(A1, B1, c3, 0, 0, 0);
        __syncthreads();
    }

    // ---- epilogue: direct float4 stores (16 lines/instr, 64 B aligned) ----
#pragma unroll
    for (int nt = 0; nt < 4; ++nt) {
        f32x4 a = (nt == 0) ? c0 : (nt == 1) ? c1 : (nt == 2) ? c2 : c3;
        int o = nt * 16 + m;
        float sc = scaleb[o];
        float bs = scaleb[Oo + o];
        float4 r;
        r.x = fmaxf(a[0] * sc + bs, 0.0f);
        r.y = fmaxf(a[1] * sc + bs, 0.0f);
        r.z = fmaxf(a[2] * sc + bs, 0.0f);
        r.w = fmaxf(a[3] * sc + bs, 0.0f);
        float* op = out + ((size_t)b * Oo + o) * HW + hw0 + wv * 16 + quad * 4;
        *(float4*)op = r;
    }
}

extern "C" void kernel_launch(void* const* d_in, const int* in_sizes, int n_in,
                              void* d_out, int out_size, void* d_ws, size_t ws_size,
                              hipStream_t stream) {
    const float* x        = (const float*)d_in[0];
    const float* w_off    = (const float*)d_in[1];
    const float* b_off    = (const float*)d_in[2];
    const float* w_dcn    = (const float*)d_in[3];
    const float* b_dcn    = (const float*)d_in[4];
    const float* gamma    = (const float*)d_in[5];
    const float* beta     = (const float*)d_in[6];
    const float* run_mean = (const float*)d_in[7];
    const float* run_var  = (const float*)d_in[8];
    float* out = (float*)d_out;

    // workspace: xhwc (26.2 MB) | wtb | woffb | scaleb
    unsigned short* xhwc  = (unsigned short*)d_ws;
    unsigned short* wtb   = xhwc + (size_t)NPIX * 64;          // 9*64*64 bf16
    unsigned short* woffb = wtb + 9 * Oo * Cc;                 // 9*32*64 bf16
    float* scaleb         = (float*)(woffb + 9 * 32 * Cc);     // 128 floats

    prep_kernel<<<(9 * Oo * Cc + 255) / 256, 256, 0, stream>>>(
        w_dcn, b_dcn, w_off, gamma, beta, run_mean, run_var, wtb, woffb, scaleb);

    xpose_kernel<<<NPIX / 64, 256, 0, stream>>>(x, xhwc);

    dcn_kernel<<<NPIX / 64, 256, 0, stream>>>(xhwc, wtb, woffb, b_off, scaleb, out);
}